// Round 1
// baseline (213.526 us; speedup 1.0000x reference)
//
#include <hip/hip_runtime.h>
#include <math.h>

// Problem constants
#define B_ 4
#define C_ 128
#define L_ 4096       // H*W
#define HEADS_ 4
#define CH_ 32
#define EPS_ 1e-5f

typedef __attribute__((ext_vector_type(8))) short short8;   // 8 x bf16 (4 VGPRs) MFMA A/B frag
typedef __attribute__((ext_vector_type(4))) float f32x4;    // MFMA C/D frag

static __device__ __forceinline__ unsigned short f2bf(float f) {
  union { float f; unsigned u; } v; v.f = f;
  return (unsigned short)((v.u + 0x7FFFu + ((v.u >> 16) & 1u)) >> 16);  // RNE
}
static __device__ __forceinline__ f32x4 fzero() {
  f32x4 z; z[0] = 0.f; z[1] = 0.f; z[2] = 0.f; z[3] = 0.f; return z;
}

// ---------------------------------------------------------------------------
// K0: GroupNorm statistics. One block per (b, g): reduces 4 ch x 4096 = 16384
// contiguous floats -> mean, rstd.
// ---------------------------------------------------------------------------
__global__ __launch_bounds__(256) void gn_stats(const float* __restrict__ x,
                                                float* __restrict__ mean,
                                                float* __restrict__ rstd) {
  int g = blockIdx.x, b = blockIdx.y;
  const f32x4* p4 = (const f32x4*)(x + (size_t)(b * C_ + g * 4) * L_);
  int tid = threadIdx.x;
  float s = 0.f, sq = 0.f;
#pragma unroll
  for (int i = 0; i < 16; ++i) {
    f32x4 v = p4[tid + i * 256];
    s += v[0] + v[1] + v[2] + v[3];
    sq += v[0]*v[0] + v[1]*v[1] + v[2]*v[2] + v[3]*v[3];
  }
#pragma unroll
  for (int m = 1; m < 64; m <<= 1) { s += __shfl_xor(s, m, 64); sq += __shfl_xor(sq, m, 64); }
  __shared__ float ls[8];
  int w = tid >> 6;
  if ((tid & 63) == 0) { ls[w] = s; ls[4 + w] = sq; }
  __syncthreads();
  if (tid == 0) {
    float S = ls[0] + ls[1] + ls[2] + ls[3];
    float Q = ls[4] + ls[5] + ls[6] + ls[7];
    float mu = S * (1.f / 16384.f);
    float var = Q * (1.f / 16384.f) - mu * mu;
    mean[b * 32 + g] = mu;
    rstd[b * 32 + g] = rsqrtf(var + EPS_);
  }
}

// ---------------------------------------------------------------------------
// K1: weights -> bf16; fold attention scale (1/sqrt(sqrt(32))) into q,k rows
// of w_qkv and into their bias.
// ---------------------------------------------------------------------------
__global__ __launch_bounds__(256) void prep_weights(const float* __restrict__ wqkv,
                                                    const float* __restrict__ bqkv,
                                                    const float* __restrict__ wproj,
                                                    unsigned short* __restrict__ wqkv_bf,
                                                    unsigned short* __restrict__ wproj_bf,
                                                    float* __restrict__ bqkv_s) {
  const float SC = 0.42044820762685725f;  // 1/sqrt(sqrt(32))
  int i = blockIdx.x * 256 + threadIdx.x;
  if (i < 49152) {
    int o = i >> 7;
    wqkv_bf[i] = f2bf(wqkv[i] * (o < 256 ? SC : 1.f));
  } else if (i < 65536) {
    wproj_bf[i - 49152] = f2bf(wproj[i - 49152]);
  } else if (i < 65920) {
    int o = i - 65536;
    bqkv_s[o] = bqkv[o] * (o < 256 ? SC : 1.f);
  }
}

// ---------------------------------------------------------------------------
// K2: fused GroupNorm-normalize + QKV 1x1 conv (GEMM M=pos N=384 K=128).
// Block: 64 pos x all 384 outputs, 4 waves (16 pos each).
// x tile staged normalized+bf16 into LDS [64 pos][128 c], XOR-swizzled so the
// MFMA A-frag ds_read_b128 (16 lanes reading 16 different rows at same col)
// is bank-conflict-free.
// Outputs: q,k (scaled) as [bh][pos][32]; v transposed as [bh][32][pos].
// ---------------------------------------------------------------------------
__global__ __launch_bounds__(256) void qkv_gemm(const float* __restrict__ x,
                                                const float* __restrict__ gamma,
                                                const float* __restrict__ beta,
                                                const float* __restrict__ mean,
                                                const float* __restrict__ rstd,
                                                const unsigned short* __restrict__ wqkv_bf,
                                                const float* __restrict__ bqkv_s,
                                                unsigned short* __restrict__ qbuf,
                                                unsigned short* __restrict__ kbuf,
                                                unsigned short* __restrict__ vtbuf) {
  __shared__ char lds[64 * 256];  // [pos][c] bf16, rows 256B, XOR-swizzled
  int b = blockIdx.y;
  int pos0 = blockIdx.x * 64;
  int tid = threadIdx.x;

  // Stage + normalize: 2048 float4 loads, coalesced along pos.
#pragma unroll
  for (int it = 0; it < 8; ++it) {
    int f4 = it * 256 + tid;         // 0..2047
    int c = f4 >> 4;                 // 0..127
    int pl = (f4 & 15) * 4;          // 0..60
    f32x4 v = *(const f32x4*)(x + (size_t)(b * C_ + c) * L_ + pos0 + pl);
    int g = c >> 2;
    float mu = mean[b * 32 + g], rs = rstd[b * 32 + g];
    float ga = gamma[c], be = beta[c];
#pragma unroll
    for (int i = 0; i < 4; ++i) {
      float hv = (v[i] - mu) * rs * ga + be;
      int row = pl + i;
      int off = row * 256 + ((c * 2) ^ ((row & 7) << 4));
      *(unsigned short*)(lds + off) = f2bf(hv);
    }
  }
  __syncthreads();

  int l = tid & 63, w = tid >> 6;
  int ln = l & 15, g4 = l >> 4;
  int lrow = w * 16 + ln;  // A-frag m-row (pos within tile)

  short8 afrag[4];
#pragma unroll
  for (int kc = 0; kc < 4; ++kc) {
    int col2 = (kc * 32 + g4 * 8) * 2;
    afrag[kc] = *(const short8*)(lds + lrow * 256 + (col2 ^ ((lrow & 7) << 4)));
  }

  f32x4 acc[24];
#pragma unroll
  for (int nt = 0; nt < 24; ++nt) acc[nt] = fzero();
#pragma unroll
  for (int nt = 0; nt < 24; ++nt) {
#pragma unroll
    for (int kc = 0; kc < 4; ++kc) {
      short8 bfrag = *(const short8*)(wqkv_bf + (size_t)(nt * 16 + ln) * 128 + kc * 32 + g4 * 8);
      acc[nt] = __builtin_amdgcn_mfma_f32_16x16x32_bf16(afrag[kc], bfrag, acc[nt], 0, 0, 0);
    }
  }

  // Epilogue: D[m=pos][n=o]: col(o-local)=ln, row(pos-local)=g4*4+reg
#pragma unroll
  for (int nt = 0; nt < 24; ++nt) {
    int o = nt * 16 + ln;
    float bias = bqkv_s[o];
#pragma unroll
    for (int r = 0; r < 4; ++r) {
      int pos = pos0 + w * 16 + g4 * 4 + r;
      unsigned short hv = f2bf(acc[nt][r] + bias);
      if (o < 128) {
        int bh = b * 4 + (o >> 5);
        qbuf[((size_t)bh * L_ + pos) * 32 + (o & 31)] = hv;
      } else if (o < 256) {
        int o2 = o - 128;
        int bh = b * 4 + (o2 >> 5);
        kbuf[((size_t)bh * L_ + pos) * 32 + (o2 & 31)] = hv;
      } else {
        int ch = o - 256;
        int bh = b * 4 + (ch >> 5);
        vtbuf[((size_t)bh * 32 + (ch & 31)) * L_ + pos] = hv;
      }
    }
  }
}

// ---------------------------------------------------------------------------
// K3: flash attention. Grid (64 q-tiles, 16 bh), 4 waves; wave owns 16 q rows.
// S = Q K^T via mfma (A=Q held in regs, B=K loaded from global: permuted-
// contiguous 1KB per load op). Online softmax with 16-lane shfl reduces.
// P goes through a per-wave XOR-swizzled LDS buffer to become the PV A-frag.
// V consumed from the transposed vtbuf. Output -> at[b][pos][c] bf16.
// ---------------------------------------------------------------------------
__global__ __launch_bounds__(256) void attn(const unsigned short* __restrict__ qbuf,
                                            const unsigned short* __restrict__ kbuf,
                                            const unsigned short* __restrict__ vtbuf,
                                            unsigned short* __restrict__ at) {
  __shared__ char plds[4][2048];  // per-wave P tile [16 q][64 kp] bf16, 128B rows
  int bh = blockIdx.y;
  int q0 = blockIdx.x * 64;
  int tid = threadIdx.x;
  int l = tid & 63, w = tid >> 6;
  int ln = l & 15, g4 = l >> 4;

  const unsigned short* qb = qbuf + (size_t)bh * L_ * 32;
  const unsigned short* kb = kbuf + (size_t)bh * L_ * 32;
  const unsigned short* vb = vtbuf + (size_t)bh * 32 * L_;

  short8 aq = *(const short8*)(qb + (size_t)(q0 + w * 16 + ln) * 32 + g4 * 8);

  f32x4 o0 = fzero(), o1 = fzero();
  float mrun[4], lrun[4];
#pragma unroll
  for (int r = 0; r < 4; ++r) { mrun[r] = -1e30f; lrun[r] = 0.f; }
  char* myp = plds[w];

  for (int kt = 0; kt < 64; ++kt) {
    int kv0 = kt * 64;
    // S tile: 4 n-tiles of 16 kpos, K=32 (full head dim) per mfma
    f32x4 s[4];
#pragma unroll
    for (int t = 0; t < 4; ++t) {
      short8 bk = *(const short8*)(kb + (size_t)(kv0 + t * 16 + ln) * 32 + g4 * 8);
      s[t] = __builtin_amdgcn_mfma_f32_16x16x32_bf16(aq, bk, fzero(), 0, 0, 0);
    }
    // Online softmax. Lane owns rows q=4*g4+r (shared by the 16 lanes of its
    // quarter-wave), cols kpos=16t+ln.
    float alpha[4];
#pragma unroll
    for (int r = 0; r < 4; ++r) {
      float mt = fmaxf(fmaxf(s[0][r], s[1][r]), fmaxf(s[2][r], s[3][r]));
      mt = fmaxf(mt, __shfl_xor(mt, 1, 64));
      mt = fmaxf(mt, __shfl_xor(mt, 2, 64));
      mt = fmaxf(mt, __shfl_xor(mt, 4, 64));
      mt = fmaxf(mt, __shfl_xor(mt, 8, 64));
      float mn = fmaxf(mrun[r], mt);
      alpha[r] = __expf(mrun[r] - mn);
      mrun[r] = mn;
      float rs = 0.f;
#pragma unroll
      for (int t = 0; t < 4; ++t) {
        float p = __expf(s[t][r] - mn);
        s[t][r] = p;
        rs += p;
      }
      rs += __shfl_xor(rs, 1, 64);
      rs += __shfl_xor(rs, 2, 64);
      rs += __shfl_xor(rs, 4, 64);
      rs += __shfl_xor(rs, 8, 64);
      lrun[r] = lrun[r] * alpha[r] + rs;
      o0[r] *= alpha[r];
      o1[r] *= alpha[r];
    }
    // P -> LDS (bf16, XOR-swizzled rows so the b128 re-read is conflict-free)
#pragma unroll
    for (int t = 0; t < 4; ++t)
#pragma unroll
      for (int r = 0; r < 4; ++r) {
        int row = g4 * 4 + r;
        int col = t * 16 + ln;
        *(unsigned short*)(myp + row * 128 + ((col * 2) ^ ((row & 7) << 4))) = f2bf(s[t][r]);
      }
    // within-wave LDS RAW: DS pipe is in-order per wave; fence the compiler
    asm volatile("s_waitcnt lgkmcnt(0)" ::: "memory");
    __builtin_amdgcn_sched_barrier(0);
    short8 pa0 = *(const short8*)(myp + ln * 128 + (((g4 * 8) * 2) ^ ((ln & 7) << 4)));
    short8 pa1 = *(const short8*)(myp + ln * 128 + (((32 + g4 * 8) * 2) ^ ((ln & 7) << 4)));
    // PV: O[16q][32d] += P[16q][64kp] * V[64kp][32d]
    short8 v00 = *(const short8*)(vb + (size_t)(ln) * L_ + kv0 + g4 * 8);
    short8 v01 = *(const short8*)(vb + (size_t)(ln) * L_ + kv0 + 32 + g4 * 8);
    short8 v10 = *(const short8*)(vb + (size_t)(16 + ln) * L_ + kv0 + g4 * 8);
    short8 v11 = *(const short8*)(vb + (size_t)(16 + ln) * L_ + kv0 + 32 + g4 * 8);
    o0 = __builtin_amdgcn_mfma_f32_16x16x32_bf16(pa0, v00, o0, 0, 0, 0);
    o0 = __builtin_amdgcn_mfma_f32_16x16x32_bf16(pa1, v01, o0, 0, 0, 0);
    o1 = __builtin_amdgcn_mfma_f32_16x16x32_bf16(pa0, v10, o1, 0, 0, 0);
    o1 = __builtin_amdgcn_mfma_f32_16x16x32_bf16(pa1, v11, o1, 0, 0, 0);
  }

  // Epilogue: divide by softmax denom, write at[b][pos][c] bf16
  int b = bh >> 2, h = bh & 3;
#pragma unroll
  for (int r = 0; r < 4; ++r) {
    float inv = 1.f / lrun[r];
    int pos = q0 + w * 16 + g4 * 4 + r;
    at[((size_t)b * L_ + pos) * 128 + h * 32 + ln] = f2bf(o0[r] * inv);
    at[((size_t)b * L_ + pos) * 128 + h * 32 + 16 + ln] = f2bf(o1[r] * inv);
  }
}

// ---------------------------------------------------------------------------
// K4: out = x + w_proj * a + b_proj. GEMM M=o(128) N=pos K=128.
// Block: 64 pos, 4 waves (16 pos each, all 128 o).
// ---------------------------------------------------------------------------
__global__ __launch_bounds__(256) void proj_residual(const float* __restrict__ x,
                                                     const unsigned short* __restrict__ at,
                                                     const unsigned short* __restrict__ wproj_bf,
                                                     const float* __restrict__ bproj,
                                                     float* __restrict__ out) {
  int b = blockIdx.y;
  int pos0 = blockIdx.x * 64;
  int tid = threadIdx.x;
  int l = tid & 63, w = tid >> 6;
  int ln = l & 15, g4 = l >> 4;
  int posw = pos0 + w * 16;

  short8 bfrag[4];
#pragma unroll
  for (int kc = 0; kc < 4; ++kc)
    bfrag[kc] = *(const short8*)(at + ((size_t)b * L_ + posw + ln) * 128 + kc * 32 + g4 * 8);

  f32x4 acc[8];
#pragma unroll
  for (int mt = 0; mt < 8; ++mt) acc[mt] = fzero();
#pragma unroll
  for (int mt = 0; mt < 8; ++mt) {
#pragma unroll
    for (int kc = 0; kc < 4; ++kc) {
      short8 afrag = *(const short8*)(wproj_bf + (size_t)(mt * 16 + ln) * 128 + kc * 32 + g4 * 8);
      acc[mt] = __builtin_amdgcn_mfma_f32_16x16x32_bf16(afrag, bfrag[kc], acc[mt], 0, 0, 0);
    }
  }
  // D[m=o][n=pos]: col(pos-local)=ln, row(o-local)=4*g4+reg
#pragma unroll
  for (int mt = 0; mt < 8; ++mt)
#pragma unroll
    for (int r = 0; r < 4; ++r) {
      int o = mt * 16 + g4 * 4 + r;
      int pos = posw + ln;
      size_t idx = ((size_t)b * C_ + o) * L_ + pos;
      out[idx] = x[idx] + acc[mt][r] + bproj[o];
    }
}

// ---------------------------------------------------------------------------
extern "C" void kernel_launch(void* const* d_in, const int* in_sizes, int n_in,
                              void* d_out, int out_size, void* d_ws, size_t ws_size,
                              hipStream_t stream) {
  const float* x     = (const float*)d_in[0];
  const float* gamma = (const float*)d_in[1];
  const float* beta  = (const float*)d_in[2];
  const float* wqkv  = (const float*)d_in[3];
  const float* bqkv  = (const float*)d_in[4];
  const float* wproj = (const float*)d_in[5];
  const float* bproj = (const float*)d_in[6];
  float* out = (float*)d_out;

  char* ws = (char*)d_ws;
  float* mean   = (float*)(ws + 0);
  float* rstd   = (float*)(ws + 512);
  float* bqkv_s = (float*)(ws + 1024);
  unsigned short* wqkv_bf = (unsigned short*)(ws + 4096);
  unsigned short* wproj_bf = (unsigned short*)(ws + 4096 + 98304);        // 102400
  unsigned short* qbuf  = (unsigned short*)(ws + 135168);
  unsigned short* kbuf  = (unsigned short*)(ws + 135168 + 4194304);       // 4329472
  unsigned short* vtbuf = (unsigned short*)(ws + 135168 + 2 * 4194304);   // 8523776
  unsigned short* at    = (unsigned short*)(ws + 135168 + 3 * 4194304);   // 12718080
  // total ws needed: 135168 + 4*4194304 = 16912384 bytes (~16.2 MB)

  gn_stats<<<dim3(32, 4), 256, 0, stream>>>(x, mean, rstd);
  prep_weights<<<dim3(258), 256, 0, stream>>>(wqkv, bqkv, wproj, wqkv_bf, wproj_bf, bqkv_s);
  qkv_gemm<<<dim3(64, 4), 256, 0, stream>>>(x, gamma, beta, mean, rstd, wqkv_bf, bqkv_s,
                                            qbuf, kbuf, vtbuf);
  attn<<<dim3(64, 16), 256, 0, stream>>>(qbuf, kbuf, vtbuf, at);
  proj_residual<<<dim3(64, 4), 256, 0, stream>>>(x, at, wproj_bf, bproj, out);
}

// Round 2
// 103.198 us; speedup vs baseline: 2.0691x; 2.0691x over previous
//
#include <hip/hip_runtime.h>
#include <math.h>

// Problem constants
#define B_ 4
#define C_ 128
#define L_ 4096       // H*W
#define HEADS_ 4
#define CH_ 32
#define EPS_ 1e-5f

typedef __attribute__((ext_vector_type(8))) short short8;   // 8 x bf16 (4 VGPRs) MFMA A/B frag
typedef __attribute__((ext_vector_type(4))) float f32x4;    // 16x16 MFMA C/D frag
typedef __attribute__((ext_vector_type(16))) float f32x16;  // 32x32 MFMA C/D frag

static __device__ __forceinline__ unsigned short f2bf(float f) {
  union { float f; unsigned u; } v; v.f = f;
  return (unsigned short)((v.u + 0x7FFFu + ((v.u >> 16) & 1u)) >> 16);  // RNE
}
static __device__ __forceinline__ f32x4 fzero() {
  f32x4 z; z[0] = 0.f; z[1] = 0.f; z[2] = 0.f; z[3] = 0.f; return z;
}
static __device__ __forceinline__ f32x16 zero16() {
  f32x16 z;
#pragma unroll
  for (int i = 0; i < 16; ++i) z[i] = 0.f;
  return z;
}
static __device__ __forceinline__ float fexp2(float x) {
#if __has_builtin(__builtin_amdgcn_exp2f)
  return __builtin_amdgcn_exp2f(x);   // v_exp_f32, one inst
#else
  return exp2f(x);
#endif
}
static __device__ __forceinline__ unsigned cvtpk(float lo, float hi) {
  unsigned r;
  asm("v_cvt_pk_bf16_f32 %0, %1, %2" : "=v"(r) : "v"(lo), "v"(hi));
  return r;
}
// vdst' = {vdst[0:31], vsrc[0:31]}, vsrc' = {vdst[32:63], vsrc[32:63]}
#define PLSWAP(a, b) asm("v_permlane32_swap_b32 %0, %1" : "+v"(a), "+v"(b))

// ---------------------------------------------------------------------------
// K0: GroupNorm statistics. One block per (b, g).
// ---------------------------------------------------------------------------
__global__ __launch_bounds__(256) void gn_stats(const float* __restrict__ x,
                                                float* __restrict__ mean,
                                                float* __restrict__ rstd) {
  int g = blockIdx.x, b = blockIdx.y;
  const f32x4* p4 = (const f32x4*)(x + (size_t)(b * C_ + g * 4) * L_);
  int tid = threadIdx.x;
  float s = 0.f, sq = 0.f;
#pragma unroll
  for (int i = 0; i < 16; ++i) {
    f32x4 v = p4[tid + i * 256];
    s += v[0] + v[1] + v[2] + v[3];
    sq += v[0]*v[0] + v[1]*v[1] + v[2]*v[2] + v[3]*v[3];
  }
#pragma unroll
  for (int m = 1; m < 64; m <<= 1) { s += __shfl_xor(s, m, 64); sq += __shfl_xor(sq, m, 64); }
  __shared__ float ls[8];
  int w = tid >> 6;
  if ((tid & 63) == 0) { ls[w] = s; ls[4 + w] = sq; }
  __syncthreads();
  if (tid == 0) {
    float S = ls[0] + ls[1] + ls[2] + ls[3];
    float Q = ls[4] + ls[5] + ls[6] + ls[7];
    float mu = S * (1.f / 16384.f);
    float var = Q * (1.f / 16384.f) - mu * mu;
    mean[b * 32 + g] = mu;
    rstd[b * 32 + g] = rsqrtf(var + EPS_);
  }
}

// ---------------------------------------------------------------------------
// K1: weights -> bf16; fold attention scale AND sqrt(log2e) into q,k rows
// (so exp(S) == exp2(S') with a single v_exp_f32).
// ---------------------------------------------------------------------------
__global__ __launch_bounds__(256) void prep_weights(const float* __restrict__ wqkv,
                                                    const float* __restrict__ bqkv,
                                                    const float* __restrict__ wproj,
                                                    unsigned short* __restrict__ wqkv_bf,
                                                    unsigned short* __restrict__ wproj_bf,
                                                    float* __restrict__ bqkv_s) {
  // 1/sqrt(sqrt(32)) * sqrt(log2(e))
  const float SC = 0.42044820762685725f * 1.2011224087864498f;
  int i = blockIdx.x * 256 + threadIdx.x;
  if (i < 49152) {
    int o = i >> 7;
    wqkv_bf[i] = f2bf(wqkv[i] * (o < 256 ? SC : 1.f));
  } else if (i < 65536) {
    wproj_bf[i - 49152] = f2bf(wproj[i - 49152]);
  } else if (i < 65920) {
    int o = i - 65536;
    bqkv_s[o] = bqkv[o] * (o < 256 ? SC : 1.f);
  }
}

// ---------------------------------------------------------------------------
// K2: fused GroupNorm-normalize + QKV 1x1 conv (GEMM M=pos N=384 K=128).
// Outputs: q,k (scaled) as [bh][pos][32]; v transposed as [bh][32][pos].
// ---------------------------------------------------------------------------
__global__ __launch_bounds__(256) void qkv_gemm(const float* __restrict__ x,
                                                const float* __restrict__ gamma,
                                                const float* __restrict__ beta,
                                                const float* __restrict__ mean,
                                                const float* __restrict__ rstd,
                                                const unsigned short* __restrict__ wqkv_bf,
                                                const float* __restrict__ bqkv_s,
                                                unsigned short* __restrict__ qbuf,
                                                unsigned short* __restrict__ kbuf,
                                                unsigned short* __restrict__ vtbuf) {
  __shared__ char lds[64 * 256];  // [pos][c] bf16, rows 256B, XOR-swizzled
  int b = blockIdx.y;
  int pos0 = blockIdx.x * 64;
  int tid = threadIdx.x;

#pragma unroll
  for (int it = 0; it < 8; ++it) {
    int f4 = it * 256 + tid;         // 0..2047
    int c = f4 >> 4;                 // 0..127
    int pl = (f4 & 15) * 4;          // 0..60
    f32x4 v = *(const f32x4*)(x + (size_t)(b * C_ + c) * L_ + pos0 + pl);
    int g = c >> 2;
    float mu = mean[b * 32 + g], rs = rstd[b * 32 + g];
    float ga = gamma[c], be = beta[c];
#pragma unroll
    for (int i = 0; i < 4; ++i) {
      float hv = (v[i] - mu) * rs * ga + be;
      int row = pl + i;
      int off = row * 256 + ((c * 2) ^ ((row & 7) << 4));
      *(unsigned short*)(lds + off) = f2bf(hv);
    }
  }
  __syncthreads();

  int l = tid & 63, w = tid >> 6;
  int ln = l & 15, g4 = l >> 4;
  int lrow = w * 16 + ln;

  short8 afrag[4];
#pragma unroll
  for (int kc = 0; kc < 4; ++kc) {
    int col2 = (kc * 32 + g4 * 8) * 2;
    afrag[kc] = *(const short8*)(lds + lrow * 256 + (col2 ^ ((lrow & 7) << 4)));
  }

  f32x4 acc[24];
#pragma unroll
  for (int nt = 0; nt < 24; ++nt) acc[nt] = fzero();
#pragma unroll
  for (int nt = 0; nt < 24; ++nt) {
#pragma unroll
    for (int kc = 0; kc < 4; ++kc) {
      short8 bfrag = *(const short8*)(wqkv_bf + (size_t)(nt * 16 + ln) * 128 + kc * 32 + g4 * 8);
      acc[nt] = __builtin_amdgcn_mfma_f32_16x16x32_bf16(afrag[kc], bfrag, acc[nt], 0, 0, 0);
    }
  }

#pragma unroll
  for (int nt = 0; nt < 24; ++nt) {
    int o = nt * 16 + ln;
    float bias = bqkv_s[o];
#pragma unroll
    for (int r = 0; r < 4; ++r) {
      int pos = pos0 + w * 16 + g4 * 4 + r;
      unsigned short hv = f2bf(acc[nt][r] + bias);
      if (o < 128) {
        int bh = b * 4 + (o >> 5);
        qbuf[((size_t)bh * L_ + pos) * 32 + (o & 31)] = hv;
      } else if (o < 256) {
        int o2 = o - 128;
        int bh = b * 4 + (o2 >> 5);
        kbuf[((size_t)bh * L_ + pos) * 32 + (o2 & 31)] = hv;
      } else {
        int ch = o - 256;
        int bh = b * 4 + (ch >> 5);
        vtbuf[((size_t)bh * 32 + (ch & 31)) * L_ + pos] = hv;
      }
    }
  }
}

// ---------------------------------------------------------------------------
// K3: flash attention, swapped-QK^T 32x32 structure.
// Grid (32 q-blocks, 16 bh), 4 waves x 32 q rows. KV tile 64, double-buffered
// in LDS (K [64kp][32d], V^T [32d][64kp], both XOR-swizzled). Softmax is
// lane-local (no max tracking: exp2 range analysis gives 2^~50 max << f32),
// P redistributed to PV B-frags via cvt_pk + permlane32_swap (T12).
// ---------------------------------------------------------------------------
#define SUBTILE(SUB, LDSBASE)                                                     \
  {                                                                               \
    const int kvl = (SUB) * 32;                                                   \
    const int krow = kvl + lq;                                                    \
    const char* kB = (LDSBASE);                                                   \
    short8 ka0 = *(const short8*)(kB + ((krow*64 + hi*16) ^ ((krow&7)<<4)));      \
    short8 ka1 = *(const short8*)(kB + ((krow*64 + 32 + hi*16) ^ ((krow&7)<<4))); \
    f32x16 s = zero16();                                                          \
    s = __builtin_amdgcn_mfma_f32_32x32x16_bf16(ka0, qf0, s, 0, 0, 0);            \
    s = __builtin_amdgcn_mfma_f32_32x32x16_bf16(ka1, qf1, s, 0, 0, 0);            \
    float p[16];                                                                  \
    _Pragma("unroll") for (int i = 0; i < 16; ++i) p[i] = fexp2(s[i]);            \
    lsum += (((p[0]+p[1])+(p[2]+p[3])) + ((p[4]+p[5])+(p[6]+p[7])))               \
          + (((p[8]+p[9])+(p[10]+p[11])) + ((p[12]+p[13])+(p[14]+p[15])));        \
    unsigned u0 = cvtpk(p[0], p[1]),  u1 = cvtpk(p[2], p[3]);                     \
    unsigned u2 = cvtpk(p[4], p[5]),  u3 = cvtpk(p[6], p[7]);                     \
    unsigned u4 = cvtpk(p[8], p[9]),  u5 = cvtpk(p[10], p[11]);                   \
    unsigned u6 = cvtpk(p[12], p[13]), u7 = cvtpk(p[14], p[15]);                  \
    PLSWAP(u0, u2); PLSWAP(u1, u3); PLSWAP(u4, u6); PLSWAP(u5, u7);               \
    union { unsigned uu[4]; short8 s8; } pa, pb;                                  \
    pa.uu[0] = u0; pa.uu[1] = u1; pa.uu[2] = u2; pa.uu[3] = u3;                   \
    pb.uu[0] = u4; pb.uu[1] = u5; pb.uu[2] = u6; pb.uu[3] = u7;                   \
    const char* vB = (LDSBASE) + 4096;                                            \
    short8 va  = *(const short8*)(vB + ((lq*128 + kvl*2 + hi*16) ^ ((lq&7)<<4))); \
    short8 vb2 = *(const short8*)(vB + ((lq*128 + kvl*2 + 32 + hi*16) ^ ((lq&7)<<4))); \
    acc = __builtin_amdgcn_mfma_f32_32x32x16_bf16(va,  pa.s8, acc, 0, 0, 0);      \
    acc = __builtin_amdgcn_mfma_f32_32x32x16_bf16(vb2, pb.s8, acc, 0, 0, 0);      \
  }

__global__ __launch_bounds__(256) void attn(const unsigned short* __restrict__ qbuf,
                                            const unsigned short* __restrict__ kbuf,
                                            const unsigned short* __restrict__ vtbuf,
                                            unsigned short* __restrict__ at) {
  __shared__ __align__(16) char lds[2][8192];  // [buf]{K 4KB, V^T 4KB}
  int bh = blockIdx.y;
  int tid = threadIdx.x;
  int l = tid & 63, w = tid >> 6;
  int lq = l & 31, hi = l >> 5;
  const unsigned short* qb = qbuf + (size_t)bh * L_ * 32;
  const unsigned short* kb = kbuf + (size_t)bh * L_ * 32;
  const unsigned short* vb = vtbuf + (size_t)bh * 32 * L_;
  int qbase = blockIdx.x * 128 + w * 32;

  // Q B-frags, held in registers for the whole kernel: B[d][q], q=lq, d=hi*8+j
  short8 qf0 = *(const short8*)(qb + (size_t)(qbase + lq) * 32 + hi * 8);
  short8 qf1 = *(const short8*)(qb + (size_t)(qbase + lq) * 32 + 16 + hi * 8);

  f32x16 acc = zero16();   // O^T[d][q] accumulator
  float lsum = 0.f;        // softmax denominator (this lane's kp-half)

  // Staging assignment: thread stages 16B of K and 16B of V^T per tile.
  int kOff = tid * 16;                           // K tile byte offset (row = tid>>2)
  int vRow = tid >> 3, vCol = (tid & 7) * 16;    // V^T tile coords (row d, byte col)

  // Prologue: stage tile 0
  f32x4 kreg = *(const f32x4*)((const char*)kb + kOff);
  f32x4 vreg = *(const f32x4*)((const char*)(vb + (size_t)vRow * L_) + vCol);
  *(f32x4*)(lds[0] + (kOff ^ (((kOff >> 6) & 7) << 4))) = kreg;
  *(f32x4*)(lds[0] + 4096 + ((vRow * 128 + vCol) ^ ((vRow & 7) << 4))) = vreg;
  __syncthreads();

  for (int kt = 0; kt < 64; ++kt) {
    char* curB = lds[kt & 1];
    if (kt < 63) {  // issue-early (T14): global loads for tile kt+1
      int kv0 = (kt + 1) * 64;
      kreg = *(const f32x4*)((const char*)kb + (size_t)kv0 * 64 + kOff);
      vreg = *(const f32x4*)((const char*)(vb + (size_t)vRow * L_ + kv0) + vCol);
    }
    SUBTILE(0, curB);
    SUBTILE(1, curB);
    if (kt < 63) {  // write-late into the other buffer
      char* nb = lds[(kt + 1) & 1];
      *(f32x4*)(nb + (kOff ^ (((kOff >> 6) & 7) << 4))) = kreg;
      *(f32x4*)(nb + 4096 + ((vRow * 128 + vCol) ^ ((vRow & 7) << 4))) = vreg;
    }
    __syncthreads();
  }

  // Combine the two kp-halves of the denominator (lane l <-> l^32)
  lsum += __shfl_xor(lsum, 32, 64);
  float inv = 1.f / lsum;

  // O^T layout: lane=q col, reg r -> d=(r&3)+8*(r>>2)+4*hi. Write at[b][pos][c].
  int b = bh >> 2, h = bh & 3;
  size_t base = ((size_t)b * L_ + qbase + lq) * 128 + h * 32;
#pragma unroll
  for (int rq = 0; rq < 4; ++rq) {
    unsigned w0 = cvtpk(acc[rq * 4 + 0] * inv, acc[rq * 4 + 1] * inv);
    unsigned w1 = cvtpk(acc[rq * 4 + 2] * inv, acc[rq * 4 + 3] * inv);
    int d0 = rq * 8 + hi * 4;
    uint2 val; val.x = w0; val.y = w1;
    *(uint2*)(at + base + d0) = val;
  }
}

// ---------------------------------------------------------------------------
// K4: out = x + w_proj * a + b_proj. GEMM M=o(128) N=pos K=128.
// ---------------------------------------------------------------------------
__global__ __launch_bounds__(256) void proj_residual(const float* __restrict__ x,
                                                     const unsigned short* __restrict__ at,
                                                     const unsigned short* __restrict__ wproj_bf,
                                                     const float* __restrict__ bproj,
                                                     float* __restrict__ out) {
  int b = blockIdx.y;
  int pos0 = blockIdx.x * 64;
  int tid = threadIdx.x;
  int l = tid & 63, w = tid >> 6;
  int ln = l & 15, g4 = l >> 4;
  int posw = pos0 + w * 16;

  short8 bfrag[4];
#pragma unroll
  for (int kc = 0; kc < 4; ++kc)
    bfrag[kc] = *(const short8*)(at + ((size_t)b * L_ + posw + ln) * 128 + kc * 32 + g4 * 8);

  f32x4 acc[8];
#pragma unroll
  for (int mt = 0; mt < 8; ++mt) acc[mt] = fzero();
#pragma unroll
  for (int mt = 0; mt < 8; ++mt) {
#pragma unroll
    for (int kc = 0; kc < 4; ++kc) {
      short8 afrag = *(const short8*)(wproj_bf + (size_t)(mt * 16 + ln) * 128 + kc * 32 + g4 * 8);
      acc[mt] = __builtin_amdgcn_mfma_f32_16x16x32_bf16(afrag, bfrag[kc], acc[mt], 0, 0, 0);
    }
  }
#pragma unroll
  for (int mt = 0; mt < 8; ++mt)
#pragma unroll
    for (int r = 0; r < 4; ++r) {
      int o = mt * 16 + g4 * 4 + r;
      int pos = posw + ln;
      size_t idx = ((size_t)b * C_ + o) * L_ + pos;
      out[idx] = x[idx] + acc[mt][r] + bproj[o];
    }
}

// ---------------------------------------------------------------------------
extern "C" void kernel_launch(void* const* d_in, const int* in_sizes, int n_in,
                              void* d_out, int out_size, void* d_ws, size_t ws_size,
                              hipStream_t stream) {
  const float* x     = (const float*)d_in[0];
  const float* gamma = (const float*)d_in[1];
  const float* beta  = (const float*)d_in[2];
  const float* wqkv  = (const float*)d_in[3];
  const float* bqkv  = (const float*)d_in[4];
  const float* wproj = (const float*)d_in[5];
  const float* bproj = (const float*)d_in[6];
  float* out = (float*)d_out;

  char* ws = (char*)d_ws;
  float* mean   = (float*)(ws + 0);
  float* rstd   = (float*)(ws + 512);
  float* bqkv_s = (float*)(ws + 1024);
  unsigned short* wqkv_bf = (unsigned short*)(ws + 4096);
  unsigned short* wproj_bf = (unsigned short*)(ws + 4096 + 98304);        // 102400
  unsigned short* qbuf  = (unsigned short*)(ws + 135168);
  unsigned short* kbuf  = (unsigned short*)(ws + 135168 + 4194304);       // 4329472
  unsigned short* vtbuf = (unsigned short*)(ws + 135168 + 2 * 4194304);   // 8523776
  unsigned short* at    = (unsigned short*)(ws + 135168 + 3 * 4194304);   // 12718080

  gn_stats<<<dim3(32, 4), 256, 0, stream>>>(x, mean, rstd);
  prep_weights<<<dim3(258), 256, 0, stream>>>(wqkv, bqkv, wproj, wqkv_bf, wproj_bf, bqkv_s);
  qkv_gemm<<<dim3(64, 4), 256, 0, stream>>>(x, gamma, beta, mean, rstd, wqkv_bf, bqkv_s,
                                            qbuf, kbuf, vtbuf);
  attn<<<dim3(32, 16), 256, 0, stream>>>(qbuf, kbuf, vtbuf, at);
  proj_residual<<<dim3(64, 4), 256, 0, stream>>>(x, at, wproj_bf, bproj, out);
}

// Round 3
// 93.655 us; speedup vs baseline: 2.2799x; 1.1019x over previous
//
#include <hip/hip_runtime.h>
#include <math.h>

// Problem constants
#define B_ 4
#define C_ 128
#define L_ 4096       // H*W
#define EPS_ 1e-5f

typedef __attribute__((ext_vector_type(8))) short short8;   // 8 x bf16 MFMA A/B frag
typedef __attribute__((ext_vector_type(4))) float f32x4;
typedef __attribute__((ext_vector_type(16))) float f32x16;  // 32x32 MFMA C/D frag

static __device__ __forceinline__ unsigned short f2bf(float f) {
  union { float f; unsigned u; } v; v.f = f;
  return (unsigned short)((v.u + 0x7FFFu + ((v.u >> 16) & 1u)) >> 16);  // RNE
}
static __device__ __forceinline__ f32x4 fzero() {
  f32x4 z; z[0] = 0.f; z[1] = 0.f; z[2] = 0.f; z[3] = 0.f; return z;
}
static __device__ __forceinline__ f32x16 zero16() {
  f32x16 z;
#pragma unroll
  for (int i = 0; i < 16; ++i) z[i] = 0.f;
  return z;
}
static __device__ __forceinline__ float fexp2(float x) {
  return __builtin_amdgcn_exp2f(x);   // v_exp_f32
}
static __device__ __forceinline__ unsigned cvtpk(float lo, float hi) {
  unsigned r;
  asm("v_cvt_pk_bf16_f32 %0, %1, %2" : "=v"(r) : "v"(lo), "v"(hi));
  return r;
}
#define PLSWAP(a, b) asm("v_permlane32_swap_b32 %0, %1" : "+v"(a), "+v"(b))

// ---------------------------------------------------------------------------
// K0: GroupNorm statistics. One block per (b, g).
// ---------------------------------------------------------------------------
__global__ __launch_bounds__(256) void gn_stats(const float* __restrict__ x,
                                                float* __restrict__ mean,
                                                float* __restrict__ rstd) {
  int g = blockIdx.x, b = blockIdx.y;
  const f32x4* p4 = (const f32x4*)(x + (size_t)(b * C_ + g * 4) * L_);
  int tid = threadIdx.x;
  float s = 0.f, sq = 0.f;
#pragma unroll
  for (int i = 0; i < 16; ++i) {
    f32x4 v = p4[tid + i * 256];
    s += v[0] + v[1] + v[2] + v[3];
    sq += v[0]*v[0] + v[1]*v[1] + v[2]*v[2] + v[3]*v[3];
  }
#pragma unroll
  for (int m = 1; m < 64; m <<= 1) { s += __shfl_xor(s, m, 64); sq += __shfl_xor(sq, m, 64); }
  __shared__ float ls[8];
  int w = tid >> 6;
  if ((tid & 63) == 0) { ls[w] = s; ls[4 + w] = sq; }
  __syncthreads();
  if (tid == 0) {
    float S = ls[0] + ls[1] + ls[2] + ls[3];
    float Q = ls[4] + ls[5] + ls[6] + ls[7];
    float mu = S * (1.f / 16384.f);
    float var = Q * (1.f / 16384.f) - mu * mu;
    mean[b * 32 + g] = mu;
    rstd[b * 32 + g] = rsqrtf(var + EPS_);
  }
}

// ---------------------------------------------------------------------------
// K1: weights -> bf16; fold attn scale * sqrt(log2e) into q,k rows + bias.
// ---------------------------------------------------------------------------
__global__ __launch_bounds__(256) void prep_weights(const float* __restrict__ wqkv,
                                                    const float* __restrict__ bqkv,
                                                    const float* __restrict__ wproj,
                                                    unsigned short* __restrict__ wqkv_bf,
                                                    unsigned short* __restrict__ wproj_bf,
                                                    float* __restrict__ bqkv_s) {
  const float SC = 0.42044820762685725f * 1.2011224087864498f;
  int i = blockIdx.x * 256 + threadIdx.x;
  if (i < 49152) {
    int o = i >> 7;
    wqkv_bf[i] = f2bf(wqkv[i] * (o < 256 ? SC : 1.f));
  } else if (i < 65536) {
    wproj_bf[i - 49152] = f2bf(wproj[i - 49152]);
  } else if (i < 65920) {
    int o = i - 65536;
    bqkv_s[o] = bqkv[o] * (o < 256 ? SC : 1.f);
  }
}

// ---------------------------------------------------------------------------
// K2: fused GroupNorm-normalize + QKV 1x1 conv. cvt_pk staging + epilogue.
// ---------------------------------------------------------------------------
__global__ __launch_bounds__(256) void qkv_gemm(const float* __restrict__ x,
                                                const float* __restrict__ gamma,
                                                const float* __restrict__ beta,
                                                const float* __restrict__ mean,
                                                const float* __restrict__ rstd,
                                                const unsigned short* __restrict__ wqkv_bf,
                                                const float* __restrict__ bqkv_s,
                                                unsigned short* __restrict__ qbuf,
                                                unsigned short* __restrict__ kbuf,
                                                unsigned short* __restrict__ vtbuf) {
  __shared__ char lds[64 * 256];  // [pos][c] bf16, rows 256B, XOR-swizzled
  int b = blockIdx.y;
  int pos0 = blockIdx.x * 64;
  int tid = threadIdx.x;

#pragma unroll
  for (int it = 0; it < 4; ++it) {
    int pi = it * 256 + tid;         // 0..1023 (c-pair, 4-pos unit)
    int c = (pi >> 4) * 2;           // even c
    int pl = (pi & 15) * 4;
    const float* xc = x + (size_t)(b * C_ + c) * L_ + pos0 + pl;
    f32x4 v0 = *(const f32x4*)xc;
    f32x4 v1 = *(const f32x4*)(xc + L_);
    int g = c >> 2;                  // c,c+1 always share a group (c even)
    float rs = rstd[b * 32 + g], mu = mean[b * 32 + g];
    float A0 = rs * gamma[c],     B0 = beta[c]     - mu * A0;
    float A1 = rs * gamma[c + 1], B1 = beta[c + 1] - mu * A1;
#pragma unroll
    for (int i = 0; i < 4; ++i) {
      int row = pl + i;
      unsigned u = cvtpk(v0[i] * A0 + B0, v1[i] * A1 + B1);
      *(unsigned*)(lds + row * 256 + ((c * 2) ^ ((row & 7) << 4))) = u;
    }
  }
  __syncthreads();

  int l = tid & 63, w = tid >> 6;
  int ln = l & 15, g4 = l >> 4;
  int lrow = w * 16 + ln;

  short8 afrag[4];
#pragma unroll
  for (int kc = 0; kc < 4; ++kc) {
    int col2 = (kc * 32 + g4 * 8) * 2;
    afrag[kc] = *(const short8*)(lds + lrow * 256 + (col2 ^ ((lrow & 7) << 4)));
  }

  f32x4 acc[24];
#pragma unroll
  for (int nt = 0; nt < 24; ++nt) acc[nt] = fzero();
#pragma unroll
  for (int nt = 0; nt < 24; ++nt) {
#pragma unroll
    for (int kc = 0; kc < 4; ++kc) {
      short8 bfrag = *(const short8*)(wqkv_bf + (size_t)(nt * 16 + ln) * 128 + kc * 32 + g4 * 8);
      acc[nt] = __builtin_amdgcn_mfma_f32_16x16x32_bf16(afrag[kc], bfrag, acc[nt], 0, 0, 0);
    }
  }

  int posb = pos0 + w * 16 + g4 * 4;
#pragma unroll
  for (int nt = 0; nt < 24; ++nt) {
    int o = nt * 16 + ln;
    float bias = bqkv_s[o];
    unsigned u01 = cvtpk(acc[nt][0] + bias, acc[nt][1] + bias);
    unsigned u23 = cvtpk(acc[nt][2] + bias, acc[nt][3] + bias);
    if (o < 128) {
      int bh = b * 4 + (o >> 5);
      unsigned short* p = qbuf + ((size_t)bh * L_ + posb) * 32 + (o & 31);
      p[0]  = (unsigned short)u01; p[32] = (unsigned short)(u01 >> 16);
      p[64] = (unsigned short)u23; p[96] = (unsigned short)(u23 >> 16);
    } else if (o < 256) {
      int o2 = o - 128;
      int bh = b * 4 + (o2 >> 5);
      unsigned short* p = kbuf + ((size_t)bh * L_ + posb) * 32 + (o2 & 31);
      p[0]  = (unsigned short)u01; p[32] = (unsigned short)(u01 >> 16);
      p[64] = (unsigned short)u23; p[96] = (unsigned short)(u23 >> 16);
    } else {
      int ch = o - 256;
      int bh = b * 4 + (ch >> 5);
      uint2 val; val.x = u01; val.y = u23;
      *(uint2*)(vtbuf + ((size_t)bh * 32 + (ch & 31)) * L_ + posb) = val;
    }
  }
}

// ---------------------------------------------------------------------------
// K3: flash attention, swapped-QK^T 32x32, no-max softmax.
// SPLIT=1: KV range split in 2 (blockIdx.z), partial O/l to workspace.
// Static double-buffer LDS (all DS addresses loop-invariant); denominator
// accumulated on the MFMA pipe via a ones-A-fragment; C=ZERO passed directly.
// ---------------------------------------------------------------------------
#define SUBT(BASE, KRa, KRb, VRa, VRb)                                            \
  {                                                                               \
    short8 ka0 = *(const short8*)((BASE) + (KRa));                                \
    short8 ka1 = *(const short8*)((BASE) + (KRb));                                \
    f32x16 s = __builtin_amdgcn_mfma_f32_32x32x16_bf16(ka0, qf0, ZERO, 0, 0, 0);  \
    s = __builtin_amdgcn_mfma_f32_32x32x16_bf16(ka1, qf1, s, 0, 0, 0);            \
    float p[16];                                                                  \
    _Pragma("unroll") for (int i = 0; i < 16; ++i) p[i] = fexp2(s[i]);            \
    unsigned u0 = cvtpk(p[0], p[1]),   u1 = cvtpk(p[2], p[3]);                    \
    unsigned u2 = cvtpk(p[4], p[5]),   u3 = cvtpk(p[6], p[7]);                    \
    unsigned u4 = cvtpk(p[8], p[9]),   u5 = cvtpk(p[10], p[11]);                  \
    unsigned u6 = cvtpk(p[12], p[13]), u7 = cvtpk(p[14], p[15]);                  \
    PLSWAP(u0, u2); PLSWAP(u1, u3); PLSWAP(u4, u6); PLSWAP(u5, u7);               \
    union { unsigned uu[4]; short8 s8; } pa, pb;                                  \
    pa.uu[0] = u0; pa.uu[1] = u1; pa.uu[2] = u2; pa.uu[3] = u3;                   \
    pb.uu[0] = u4; pb.uu[1] = u5; pb.uu[2] = u6; pb.uu[3] = u7;                   \
    short8 va  = *(const short8*)((BASE) + (VRa));                                \
    short8 vb2 = *(const short8*)((BASE) + (VRb));                                \
    acc  = __builtin_amdgcn_mfma_f32_32x32x16_bf16(va,  pa.s8, acc, 0, 0, 0);     \
    acc  = __builtin_amdgcn_mfma_f32_32x32x16_bf16(vb2, pb.s8, acc, 0, 0, 0);     \
    lacc = __builtin_amdgcn_mfma_f32_32x32x16_bf16(ONESF, pa.s8, lacc, 0, 0, 0);  \
    lacc = __builtin_amdgcn_mfma_f32_32x32x16_bf16(ONESF, pb.s8, lacc, 0, 0, 0);  \
  }

template <int SPLIT>
__global__ __launch_bounds__(256, 4) void attn_k(const unsigned short* __restrict__ qbuf,
                                                 const unsigned short* __restrict__ kbuf,
                                                 const unsigned short* __restrict__ vtbuf,
                                                 unsigned short* __restrict__ at,
                                                 float* __restrict__ pO,
                                                 float* __restrict__ pL) {
  __shared__ __align__(16) char ldsA[8192];  // {K 4KB, V^T 4KB}
  __shared__ __align__(16) char ldsB[8192];
  const int bh = blockIdx.y;
  const int half = SPLIT ? blockIdx.z : 0;
  const int NT = SPLIT ? 32 : 64;
  const int tid = threadIdx.x;
  const int l = tid & 63, w = tid >> 6;
  const int lq = l & 31, hi = l >> 5;

  const char* kbB = (const char*)(kbuf + (size_t)bh * L_ * 32) + (size_t)half * NT * 4096;
  const char* vbB = (const char*)(vtbuf + (size_t)bh * 32 * L_) + (size_t)half * NT * 128;
  const unsigned short* qb = qbuf + (size_t)bh * L_ * 32;
  int qbase = blockIdx.x * 128 + w * 32;

  short8 qf0 = *(const short8*)(qb + (size_t)(qbase + lq) * 32 + hi * 8);
  short8 qf1 = *(const short8*)(qb + (size_t)(qbase + lq) * 32 + 16 + hi * 8);

  short8 ONESF;
#pragma unroll
  for (int i = 0; i < 8; ++i) ONESF[i] = (short)0x3F80;  // bf16 1.0
  const f32x16 ZERO = zero16();
  f32x16 acc = zero16();   // O^T[d][q] (unnormalized)
  f32x16 lacc = zero16();  // denominator sums, replicated across rows

  // staging: thread stages 16B of K and 16B of V^T per tile
  const int kOff = tid * 16;
  const int kWoff = kOff ^ (((kOff >> 6) & 7) << 4);
  const int vRow = tid >> 3;
  const int vCol = (tid & 7) * 16;
  const int vWoff = 4096 + ((vRow * 128 + vCol) ^ ((vRow & 7) << 4));
  const char* vRowBase = vbB + (size_t)vRow * (L_ * 2);

  // loop-invariant LDS read offsets (note (32+lq)&7 == lq&7)
  const int swz = (lq & 7) << 4;
  const int kR0a = (lq * 64 + hi * 16) ^ swz;
  const int kR0b = (lq * 64 + 32 + hi * 16) ^ swz;
  const int kR1a = ((32 + lq) * 64 + hi * 16) ^ swz;
  const int kR1b = ((32 + lq) * 64 + 32 + hi * 16) ^ swz;
  const int vR0a = 4096 + ((lq * 128 + hi * 16) ^ swz);
  const int vR0b = 4096 + ((lq * 128 + 32 + hi * 16) ^ swz);
  const int vR1a = 4096 + ((lq * 128 + 64 + hi * 16) ^ swz);
  const int vR1b = 4096 + ((lq * 128 + 96 + hi * 16) ^ swz);

  // prologue: stage tile 0 into A
  f32x4 kreg = *(const f32x4*)(kbB + kOff);
  f32x4 vreg = *(const f32x4*)(vRowBase + vCol);
  *(f32x4*)(ldsA + kWoff) = kreg;
  *(f32x4*)(ldsA + vWoff) = vreg;
  __syncthreads();

  for (int kt = 0; kt < NT; kt += 2) {
    int t1 = (kt + 1 < NT) ? kt + 1 : NT - 1;
    kreg = *(const f32x4*)(kbB + t1 * 4096 + kOff);
    vreg = *(const f32x4*)(vRowBase + t1 * 128 + vCol);
    SUBT(ldsA, kR0a, kR0b, vR0a, vR0b);
    SUBT(ldsA, kR1a, kR1b, vR1a, vR1b);
    *(f32x4*)(ldsB + kWoff) = kreg;
    *(f32x4*)(ldsB + vWoff) = vreg;
    __syncthreads();
    int t2 = (kt + 2 < NT) ? kt + 2 : NT - 1;
    kreg = *(const f32x4*)(kbB + t2 * 4096 + kOff);
    vreg = *(const f32x4*)(vRowBase + t2 * 128 + vCol);
    SUBT(ldsB, kR0a, kR0b, vR0a, vR0b);
    SUBT(ldsB, kR1a, kR1b, vR1a, vR1b);
    *(f32x4*)(ldsA + kWoff) = kreg;
    *(f32x4*)(ldsA + vWoff) = vreg;
    __syncthreads();
  }

  if (SPLIT) {
    float* po = pO + (size_t)(bh * 2 + half) * 32 * 4096 + qbase + lq;
#pragma unroll
    for (int r = 0; r < 16; ++r) {
      int d = (r & 3) + 8 * (r >> 2) + 4 * hi;
      po[(size_t)d * 4096] = acc[r];
    }
    if (hi == 0) pL[(size_t)(bh * 2 + half) * 4096 + qbase + lq] = lacc[0];
  } else {
    float inv = 1.f / lacc[0];   // ones-MFMA already summed over both hi halves
    int b = bh >> 2, h = bh & 3;
    size_t base = ((size_t)b * L_ + qbase + lq) * 128 + h * 32;
#pragma unroll
    for (int rq = 0; rq < 4; ++rq) {
      unsigned w0 = cvtpk(acc[rq * 4 + 0] * inv, acc[rq * 4 + 1] * inv);
      unsigned w1 = cvtpk(acc[rq * 4 + 2] * inv, acc[rq * 4 + 3] * inv);
      uint2 val; val.x = w0; val.y = w1;
      *(uint2*)(at + base + rq * 8 + hi * 4) = val;
    }
  }
}

// ---------------------------------------------------------------------------
// K3b: combine the two KV-half partials -> at[b][pos][c] bf16.
// ---------------------------------------------------------------------------
__global__ __launch_bounds__(256) void attn_combine(const float* __restrict__ pO,
                                                    const float* __restrict__ pL,
                                                    unsigned short* __restrict__ at) {
  int bh = blockIdx.y;
  int q = blockIdx.x * 256 + threadIdx.x;
  float inv = 1.f / (pL[(size_t)(bh * 2) * 4096 + q] + pL[(size_t)(bh * 2 + 1) * 4096 + q]);
  const float* p0 = pO + (size_t)(bh * 2) * 32 * 4096 + q;
  const float* p1 = p0 + 32 * 4096;
  int b = bh >> 2, h = bh & 3;
  unsigned short* dst = at + ((size_t)b * L_ + q) * 128 + h * 32;
#pragma unroll
  for (int d = 0; d < 32; d += 2) {
    float a0 = (p0[(size_t)d * 4096] + p1[(size_t)d * 4096]) * inv;
    float a1 = (p0[(size_t)(d + 1) * 4096] + p1[(size_t)(d + 1) * 4096]) * inv;
    *(unsigned*)(dst + d) = cvtpk(a0, a1);
  }
}

// ---------------------------------------------------------------------------
// K4: out = x + w_proj * a + b_proj.
// ---------------------------------------------------------------------------
__global__ __launch_bounds__(256) void proj_residual(const float* __restrict__ x,
                                                     const unsigned short* __restrict__ at,
                                                     const unsigned short* __restrict__ wproj_bf,
                                                     const float* __restrict__ bproj,
                                                     float* __restrict__ out) {
  int b = blockIdx.y;
  int pos0 = blockIdx.x * 64;
  int tid = threadIdx.x;
  int l = tid & 63, w = tid >> 6;
  int ln = l & 15, g4 = l >> 4;
  int posw = pos0 + w * 16;

  short8 bfrag[4];
#pragma unroll
  for (int kc = 0; kc < 4; ++kc)
    bfrag[kc] = *(const short8*)(at + ((size_t)b * L_ + posw + ln) * 128 + kc * 32 + g4 * 8);

  f32x4 acc[8];
#pragma unroll
  for (int mt = 0; mt < 8; ++mt) acc[mt] = fzero();
#pragma unroll
  for (int mt = 0; mt < 8; ++mt) {
#pragma unroll
    for (int kc = 0; kc < 4; ++kc) {
      short8 afrag = *(const short8*)(wproj_bf + (size_t)(mt * 16 + ln) * 128 + kc * 32 + g4 * 8);
      acc[mt] = __builtin_amdgcn_mfma_f32_16x16x32_bf16(afrag, bfrag[kc], acc[mt], 0, 0, 0);
    }
  }
#pragma unroll
  for (int mt = 0; mt < 8; ++mt)
#pragma unroll
    for (int r = 0; r < 4; ++r) {
      int o = mt * 16 + g4 * 4 + r;
      int pos = posw + ln;
      size_t idx = ((size_t)b * C_ + o) * L_ + pos;
      out[idx] = x[idx] + acc[mt][r] + bproj[o];
    }
}

// ---------------------------------------------------------------------------
extern "C" void kernel_launch(void* const* d_in, const int* in_sizes, int n_in,
                              void* d_out, int out_size, void* d_ws, size_t ws_size,
                              hipStream_t stream) {
  const float* x     = (const float*)d_in[0];
  const float* gamma = (const float*)d_in[1];
  const float* beta  = (const float*)d_in[2];
  const float* wqkv  = (const float*)d_in[3];
  const float* bqkv  = (const float*)d_in[4];
  const float* wproj = (const float*)d_in[5];
  const float* bproj = (const float*)d_in[6];
  float* out = (float*)d_out;

  char* ws = (char*)d_ws;
  float* mean   = (float*)(ws + 0);
  float* rstd   = (float*)(ws + 512);
  float* bqkv_s = (float*)(ws + 1024);
  unsigned short* wqkv_bf  = (unsigned short*)(ws + 4096);
  unsigned short* wproj_bf = (unsigned short*)(ws + 102400);
  unsigned short* qbuf  = (unsigned short*)(ws + 135168);
  unsigned short* kbuf  = (unsigned short*)(ws + 135168 + 4194304);
  unsigned short* vtbuf = (unsigned short*)(ws + 135168 + 2 * 4194304);
  unsigned short* at    = (unsigned short*)(ws + 135168 + 3 * 4194304);
  float* pO = (float*)(ws + 16912384);            // 16.78 MB: [16bh][2][32d][4096q] f32
  float* pL = (float*)(ws + 16912384 + 16777216); // 512 KB:  [16bh][2][4096q] f32
  const bool split = ws_size >= 34213888ull;      // partials fit?

  gn_stats<<<dim3(32, 4), 256, 0, stream>>>(x, mean, rstd);
  prep_weights<<<dim3(258), 256, 0, stream>>>(wqkv, bqkv, wproj, wqkv_bf, wproj_bf, bqkv_s);
  qkv_gemm<<<dim3(64, 4), 256, 0, stream>>>(x, gamma, beta, mean, rstd, wqkv_bf, bqkv_s,
                                            qbuf, kbuf, vtbuf);
  if (split) {
    attn_k<1><<<dim3(32, 16, 2), 256, 0, stream>>>(qbuf, kbuf, vtbuf, at, pO, pL);
    attn_combine<<<dim3(16, 16), 256, 0, stream>>>(pO, pL, at);
  } else {
    attn_k<0><<<dim3(32, 16), 256, 0, stream>>>(qbuf, kbuf, vtbuf, at, pO, pL);
  }
  proj_residual<<<dim3(64, 4), 256, 0, stream>>>(x, at, wproj_bf, bproj, out);
}